// Round 1
// baseline (655.662 us; speedup 1.0000x reference)
//
#include <hip/hip_runtime.h>

// upfirdn2d: UP=2, DOWN=1, KS=4, pad=(1,2). Input (16,128,128,128) f32 NCHW.
// XLA lhs_dilation: out spatial = (H-1)*2+1 + 3 - 4 + 1 = 255 (derived at
// launch from out_size as a hedge).
//
// Each thread owns input pixel (iy,ix) and produces the 2x2 output tile at
// (2iy,2ix) from the input quad a=x[iy][ix], b=x[iy][ix+1], c=x[iy+1][ix],
// d=x[iy+1][ix+1] (OOB -> 0):
//   out[2iy  ][2ix  ] = K11 a + K13 b + K31 c + K33 d
//   out[2iy  ][2ix+1] = K10 a + K12 b + K30 c + K32 d
//   out[2iy+1][2ix  ] = K01 a + K03 b + K21 c + K23 d
//   out[2iy+1][2ix+1] = K00 a + K02 b + K20 c + K22 d
// where K[ky][kx] is the 4x4 outer-product kernel (symmetric, so no
// conv-vs-corr flip concern).

#define IH 128
#define IW 128

__global__ __launch_bounds__(256) void blur_up2_kernel(
    const float* __restrict__ in, const float* __restrict__ ker,
    float* __restrict__ out, int oh, int ow) {
    int id = blockIdx.x * 256 + threadIdx.x;
    int ix = id & (IW - 1);
    int iy = (id >> 7) & (IH - 1);
    int nc = id >> 14;  // n*C + c, 0..2047

    const float* ib = in + (size_t)nc * (IH * IW) + (size_t)iy * IW + ix;
    bool xin = (ix < IW - 1);
    bool yin = (iy < IH - 1);

    float a = ib[0];
    float b = xin ? ib[1] : 0.f;
    float c = yin ? ib[IW] : 0.f;
    float d = (xin && yin) ? ib[IW + 1] : 0.f;

    // 4x4 kernel, uniform address -> cached broadcast
    float K00 = ker[0],  K01 = ker[1],  K02 = ker[2],  K03 = ker[3];
    float K10 = ker[4],  K11 = ker[5],  K12 = ker[6],  K13 = ker[7];
    float K20 = ker[8],  K21 = ker[9],  K22 = ker[10], K23 = ker[11];
    float K30 = ker[12], K31 = ker[13], K32 = ker[14], K33 = ker[15];

    float o00 = K11 * a + K13 * b + K31 * c + K33 * d;
    float o01 = K10 * a + K12 * b + K30 * c + K32 * d;
    float o10 = K01 * a + K03 * b + K21 * c + K23 * d;
    float o11 = K00 * a + K02 * b + K20 * c + K22 * d;

    int ox = 2 * ix, oy = 2 * iy;
    size_t ob = (size_t)nc * ((size_t)oh * ow) + (size_t)oy * ow + ox;
    bool xs = (ox + 1 < ow);   // store guard for odd output col
    bool ys = (oy + 1 < oh);   // store guard for odd output row

    out[ob] = o00;
    if (xs) out[ob + 1] = o01;
    if (ys) out[ob + ow] = o10;
    if (xs && ys) out[ob + ow + 1] = o11;
}

extern "C" void kernel_launch(void* const* d_in, const int* in_sizes, int n_in,
                              void* d_out, int out_size, void* d_ws, size_t ws_size,
                              hipStream_t stream) {
    const float* imgs = (const float*)d_in[0];
    const float* ker  = (const float*)d_in[1];
    float* out        = (float*)d_out;

    const int NC = 16 * 128;
    int ohw = out_size / NC;          // OH*OW, square
    int ow = (ohw == 256 * 256) ? 256 : 255;  // hedge 255 vs 256
    int oh = ow;

    int total = NC * IH * IW;          // 33,554,432 threads
    int blocks = total / 256;          // 131,072
    blur_up2_kernel<<<blocks, 256, 0, stream>>>(imgs, ker, out, oh, ow);
}